// Round 4
// baseline (228.091 us; speedup 1.0000x reference)
//
#include <hip/hip_runtime.h>

#define N_NODES 100000
#define E_EDGES 1600000
#define C 128
#define BSHIFT 9
#define BMASK 511
#define BNODES 512
#define NBKT 196      // ceil(N/512)
#define CAP 12288     // per-bucket padded capacity: mean 8163 + 391*7.5 pad ~= 11.1K, +13 sigma
#define LCAP 64

#define PA_BLOCKS 391     // passA role: 4096 edges per 512-thr block
#define PACK_BLOCKS 8     // pack role: 4096 frag-items

#define PB_BLOCKS 196     // passB role (1024-thr): one block per bucket
#define CVT_BLOCKS 1563   // cvt role (1024-thr): 1.6M uint4

typedef __attribute__((ext_vector_type(8))) short short8;   // 8 bf16 (4 VGPRs)
typedef __attribute__((ext_vector_type(4))) float f32x4;    // MFMA acc

__device__ __forceinline__ unsigned short f2bf(float f) {  // RNE fp32->bf16
  unsigned int b = __float_as_uint(f);
  return (unsigned short)((b + 0x7fffu + ((b >> 16) & 1u)) >> 16);
}
__device__ __forceinline__ float bflo(unsigned int v) {
  return __uint_as_float(v << 16);
}
__device__ __forceinline__ float bfhi(unsigned int v) {
  return __uint_as_float(v & 0xffff0000u);
}

// ---------------------------------------------------------------------------
// Dispatch 1: passA2 + pack.
// passA2 = R0's LDS multisplit, but with LINE-PRIVATE padded runs: each block
// allocates (v+15)&~15 slots per bucket, so every run starts 64B-aligned and
// spans whole lines. No cache line is written by two blocks -> no cross-XCD
// tail-line ping-pong (the theory for passA's measured ~90us vs ~15us
// roofline). Pad slots get -1 sentinels; consumers skip negatives.
// ---------------------------------------------------------------------------
__global__ __launch_bounds__(512) void passA_kernel(
    const int* __restrict__ erow, const int* __restrict__ ecol,
    const float* __restrict__ W_l, const float* __restrict__ W_r,
    ushort* __restrict__ Bp, int* __restrict__ bcnt, int* __restrict__ pairs) {
  __shared__ int cnt[NBKT], pos[NBKT], loff[256], total;
  __shared__ int lbuf[4096];
  __shared__ int gaddr[4096];
  int bid = blockIdx.x;
  int tid = threadIdx.x;

  if (bid < PA_BLOCKS) {
    for (int b = tid; b < NBKT; b += 512) cnt[b] = 0;
    __syncthreads();

    // Two int4s per thread, strided for coalescing: edges [bid*4096, +4096).
    int i0 = bid * 1024 + tid;
    int i1 = i0 + 512;
    bool ok0 = (i0 < E_EDGES / 4), ok1 = (i1 < E_EDGES / 4);
    int4 r0, c0, r1, c1;
    int bk[8], rk[8];
    if (ok0) {
      r0 = ((const int4*)erow)[i0];
      c0 = ((const int4*)ecol)[i0];
      bk[0] = r0.x >> BSHIFT; rk[0] = atomicAdd(&cnt[bk[0]], 1);
      bk[1] = r0.y >> BSHIFT; rk[1] = atomicAdd(&cnt[bk[1]], 1);
      bk[2] = r0.z >> BSHIFT; rk[2] = atomicAdd(&cnt[bk[2]], 1);
      bk[3] = r0.w >> BSHIFT; rk[3] = atomicAdd(&cnt[bk[3]], 1);
    }
    if (ok1) {
      r1 = ((const int4*)erow)[i1];
      c1 = ((const int4*)ecol)[i1];
      bk[4] = r1.x >> BSHIFT; rk[4] = atomicAdd(&cnt[bk[4]], 1);
      bk[5] = r1.y >> BSHIFT; rk[5] = atomicAdd(&cnt[bk[5]], 1);
      bk[6] = r1.z >> BSHIFT; rk[6] = atomicAdd(&cnt[bk[6]], 1);
      bk[7] = r1.w >> BSHIFT; rk[7] = atomicAdd(&cnt[bk[7]], 1);
    }
    __syncthreads();

    // Per-bucket PADDED chunk alloc (16-int multiples -> 64B-aligned,
    // line-private runs) + parallel exclusive scan of cnt -> loff.
    int v = 0;
    if (tid < 256) {
      v = (tid < NBKT) ? cnt[tid] : 0;
      loff[tid] = v;
      if (tid < NBKT) {
        int pv = (v + 15) & ~15;
        pos[tid] = atomicAdd(&bcnt[tid], pv);
      }
    }
    __syncthreads();
    for (int d = 1; d < 256; d <<= 1) {
      int u = (tid < 256 && tid >= d) ? loff[tid - d] : 0;
      __syncthreads();
      if (tid < 256) loff[tid] += u;
      __syncthreads();
    }
    if (tid < 256) loff[tid] -= v;  // own-slot exclusive (no race)
    if (tid == NBKT - 1) total = loff[tid] + v;
    __syncthreads();

    if (ok0) {
      int src[4] = {c0.x, c0.y, c0.z, c0.w};
      int dst[4] = {r0.x, r0.y, r0.z, r0.w};
#pragma unroll
      for (int i = 0; i < 4; ++i) {
        int s = loff[bk[i]] + rk[i];
        lbuf[s] = (src[i] << BSHIFT) | (dst[i] & BMASK);
        int g = pos[bk[i]] + rk[i];
        gaddr[s] = (g < CAP) ? bk[i] * CAP + g : -1;  // overflow guard
      }
    }
    if (ok1) {
      int src[4] = {c1.x, c1.y, c1.z, c1.w};
      int dst[4] = {r1.x, r1.y, r1.z, r1.w};
#pragma unroll
      for (int i = 0; i < 4; ++i) {
        int s = loff[bk[4 + i]] + rk[4 + i];
        lbuf[s] = (src[i] << BSHIFT) | (dst[i] & BMASK);
        int g = pos[bk[4 + i]] + rk[4 + i];
        gaddr[s] = (g < CAP) ? bk[4 + i] * CAP + g : -1;
      }
    }
    __syncthreads();

    int tot = total;
    for (int i = tid; i < tot; i += 512) {
      int g = gaddr[i];
      if (g >= 0) pairs[g] = lbuf[i];  // block-private, line-aligned runs
    }
    // Sentinel-fill the pad tail of this block's runs (block-private lines).
    if (tid < NBKT) {
      int vv = cnt[tid];
      int pv = (vv + 15) & ~15;
      int base = pos[tid];
      for (int r = vv; r < pv; ++r) {
        int g = base + r;
        if (g < CAP) pairs[tid * CAP + g] = -1;
      }
    }
  } else {
    // ---- pack Wcat=[W_l;W_r] into MFMA B-fragment order (unchanged).
    int t = (bid - PA_BLOCKS) * 512 + tid;  // t < 4096
    int Cb = t >> 9, kb = (t >> 6) & 7, lane = t & 63;
    int n = Cb * 16 + (lane & 15);
    int k0 = kb * 32 + (lane >> 4) * 8;
    ushort u[8];
#pragma unroll
    for (int j = 0; j < 8; ++j) {
      int k = k0 + j;
      float w = (k < C) ? W_l[k * C + n] : W_r[(k - C) * C + n];
      u[j] = f2bf(w);
    }
    ((uint4*)Bp)[t] = *(const uint4*)u;
  }
}

// ---------------------------------------------------------------------------
// Dispatch 2: passB-slim (sentinel-skip) + cvt co-dispatched (R2-verified).
// passB: scan-free padded-CSR build; ssrc node windows are bucket-private
// (one block), so writes stay in one XCD's L2 and merge to full lines.
// ---------------------------------------------------------------------------
__global__ __launch_bounds__(1024) void passB_kernel(
    const int* __restrict__ pairs, const int* __restrict__ bcnt,
    const float* __restrict__ x, ushort* __restrict__ xh,
    int* __restrict__ deg, int* __restrict__ ssrc, int capn) {
  __shared__ int l[BNODES];
  int bid = blockIdx.x;
  int t = threadIdx.x;

  if (bid < PB_BLOCKS) {
    int b = bid;
    if (t < BNODES) l[t] = 0;
    __syncthreads();

    int nbase = b << BSHIFT;
    int nn = min(BNODES, N_NODES - nbase);
    int cntb = min(bcnt[b], CAP);   // padded length (multiple of 16)
    const int* bp = pairs + b * CAP;
    int wbase = nbase * capn;

    for (int e = t; e < cntb; e += 1024) {
      int p = bp[e];
      if (p >= 0) {                 // skip pad sentinels
        int loc = p & BMASK;
        int slot = atomicAdd(&l[loc], 1);
        if (slot < capn) ssrc[wbase + loc * capn + slot] = p >> BSHIFT;
      }
    }
    __syncthreads();
    if (t < nn) deg[nbase + t] = l[t];
  } else {
    // ---- cvt: x fp32 -> xh bf16 (77 MB stream).
    int t2 = (bid - PB_BLOCKS) * 1024 + t;
    if (t2 < (N_NODES * C) / 8) {
      float4 a = ((const float4*)x)[2 * t2];
      float4 b = ((const float4*)x)[2 * t2 + 1];
      ushort u[8] = {f2bf(a.x), f2bf(a.y), f2bf(a.z), f2bf(a.w),
                     f2bf(b.x), f2bf(b.y), f2bf(b.z), f2bf(b.w)};
      ((uint4*)xh)[t2] = *(const uint4*)u;
    }
  }
}

// ---------------------------------------------------------------------------
// Fused gather-mean + MFMA GEMM:  out = relu([agg|x] @ [W_l;W_r] + b_l)
// R2-verified form (padded-CSR consumer) + 4-deep gather pipelining:
// the gather is latency-bound (5.3 B/cy/CU, VALU 38%), so 4 uint4 loads in
// flight per lane instead of 2. deg~16 -> one 4-deep iteration per node.
// ---------------------------------------------------------------------------
__global__ __launch_bounds__(256) void fused_kernel(
    const ushort* __restrict__ xh, const int* __restrict__ deg,
    const int* __restrict__ ssrc, const ushort* __restrict__ Bp,
    const float* __restrict__ b_l, float* __restrict__ out, int capn) {
  __shared__ ushort lA[32][264];
  int tid = threadIdx.x;
  int lane = tid & 63;
  int wave = tid >> 6;
  long base = (long)blockIdx.x * 32;

  for (int i = tid; i < 32 * 16; i += 256) {
    int r = i >> 4, q = i & 15;
    uint4 v = ((const uint4*)(xh + (base + r) * C))[q];
    *(uint4*)&lA[r][128 + q * 8] = v;
  }

  int l4 = lane & 15;   // channel group: ch [l4*8, l4*8+8)
  int q = lane >> 4;    // quarter: edge stripe

  for (int j = 0; j < 8; ++j) {
    int n = wave * 8 + j;
    int row = (int)base + n;
    int dg = deg[row];
    int e0 = row * capn;                 // <= 100000*64, fits int
    int e1 = e0 + min(dg, capn);
    float s[8];
#pragma unroll
    for (int i = 0; i < 8; ++i) s[i] = 0.0f;

    int e = e0 + q;
    for (; e + 12 < e1; e += 16) {  // 4 uint4 gathers in flight per lane
      int sa = ssrc[e];
      int sb = ssrc[e + 4];
      int sc = ssrc[e + 8];
      int sd = ssrc[e + 12];
      uint4 va = ((const uint4*)(xh + (long)sa * C))[l4];
      uint4 vb = ((const uint4*)(xh + (long)sb * C))[l4];
      uint4 vc = ((const uint4*)(xh + (long)sc * C))[l4];
      uint4 vd = ((const uint4*)(xh + (long)sd * C))[l4];
      s[0] += (bflo(va.x) + bflo(vb.x)) + (bflo(vc.x) + bflo(vd.x));
      s[1] += (bfhi(va.x) + bfhi(vb.x)) + (bfhi(vc.x) + bfhi(vd.x));
      s[2] += (bflo(va.y) + bflo(vb.y)) + (bflo(vc.y) + bflo(vd.y));
      s[3] += (bfhi(va.y) + bfhi(vb.y)) + (bfhi(vc.y) + bfhi(vd.y));
      s[4] += (bflo(va.z) + bflo(vb.z)) + (bflo(vc.z) + bflo(vd.z));
      s[5] += (bfhi(va.z) + bfhi(vb.z)) + (bfhi(vc.z) + bfhi(vd.z));
      s[6] += (bflo(va.w) + bflo(vb.w)) + (bflo(vc.w) + bflo(vd.w));
      s[7] += (bfhi(va.w) + bfhi(vb.w)) + (bfhi(vc.w) + bfhi(vd.w));
    }
    for (; e + 4 < e1; e += 8) {   // 2-deep
      int sa = ssrc[e];
      int sb = ssrc[e + 4];
      uint4 va = ((const uint4*)(xh + (long)sa * C))[l4];
      uint4 vb = ((const uint4*)(xh + (long)sb * C))[l4];
      s[0] += bflo(va.x) + bflo(vb.x); s[1] += bfhi(va.x) + bfhi(vb.x);
      s[2] += bflo(va.y) + bflo(vb.y); s[3] += bfhi(va.y) + bfhi(vb.y);
      s[4] += bflo(va.z) + bflo(vb.z); s[5] += bfhi(va.z) + bfhi(vb.z);
      s[6] += bflo(va.w) + bflo(vb.w); s[7] += bfhi(va.w) + bfhi(vb.w);
    }
    if (e < e1) {
      int sa = ssrc[e];
      uint4 va = ((const uint4*)(xh + (long)sa * C))[l4];
      s[0] += bflo(va.x); s[1] += bfhi(va.x);
      s[2] += bflo(va.y); s[3] += bfhi(va.y);
      s[4] += bflo(va.z); s[5] += bfhi(va.z);
      s[6] += bflo(va.w); s[7] += bfhi(va.w);
    }
#pragma unroll
    for (int i = 0; i < 8; ++i) {
      s[i] += __shfl_xor(s[i], 16);
      s[i] += __shfl_xor(s[i], 32);
    }
    float inv = 1.0f / fmaxf((float)dg, 1.0f);  // true degree (mean agg)
    if (q == 0) {
      ushort u[8];
#pragma unroll
      for (int i = 0; i < 8; ++i) u[i] = f2bf(s[i] * inv);
      *(uint4*)&lA[n][l4 * 8] = *(const uint4*)u;
    }
  }
  __syncthreads();

  f32x4 acc0 = {0, 0, 0, 0}, acc1 = {0, 0, 0, 0};
  f32x4 acc2 = {0, 0, 0, 0}, acc3 = {0, 0, 0, 0};
  int m = lane & 15, quad = lane >> 4;
  const ushort* bp0 = Bp + (((2 * wave + 0) * 8) * 64 + lane) * 8;
  const ushort* bp1 = Bp + (((2 * wave + 1) * 8) * 64 + lane) * 8;
#pragma unroll
  for (int kb = 0; kb < 8; ++kb) {
    short8 a0 = *(const short8*)&lA[m][kb * 32 + quad * 8];
    short8 a1 = *(const short8*)&lA[16 + m][kb * 32 + quad * 8];
    short8 b0 = *(const short8*)(bp0 + kb * 64 * 8);
    short8 b1 = *(const short8*)(bp1 + kb * 64 * 8);
    acc0 = __builtin_amdgcn_mfma_f32_16x16x32_bf16(a0, b0, acc0, 0, 0, 0);
    acc1 = __builtin_amdgcn_mfma_f32_16x16x32_bf16(a0, b1, acc1, 0, 0, 0);
    acc2 = __builtin_amdgcn_mfma_f32_16x16x32_bf16(a1, b0, acc2, 0, 0, 0);
    acc3 = __builtin_amdgcn_mfma_f32_16x16x32_bf16(a1, b1, acc3, 0, 0, 0);
  }

  int col0 = (2 * wave + 0) * 16 + m;
  int col1 = col0 + 16;
  float bl0 = b_l[col0], bl1 = b_l[col1];
#pragma unroll
  for (int r = 0; r < 4; ++r) {
    long row0 = base + quad * 4 + r;
    long row1 = row0 + 16;
    out[row0 * C + col0] = fmaxf(acc0[r] + bl0, 0.0f);
    out[row0 * C + col1] = fmaxf(acc1[r] + bl1, 0.0f);
    out[row1 * C + col0] = fmaxf(acc2[r] + bl0, 0.0f);
    out[row1 * C + col1] = fmaxf(acc3[r] + bl1, 0.0f);
  }
}

extern "C" void kernel_launch(void* const* d_in, const int* in_sizes, int n_in,
                              void* d_out, int out_size, void* d_ws, size_t ws_size,
                              hipStream_t stream) {
  const float* x   = (const float*)d_in[0];
  const int* erow  = (const int*)d_in[1];   // dst
  const int* ecol  = (const int*)d_in[2];   // src
  const float* W_l = (const float*)d_in[3];
  const float* b_l = (const float*)d_in[4];
  const float* W_r = (const float*)d_in[5];
  float* out = (float*)d_out;

  char* p = (char*)d_ws;
  ushort* xh  = (ushort*)p;  p += (size_t)N_NODES * C * 2;      // 25.6 MB
  ushort* Bp  = (ushort*)p;  p += 2 * C * C * 2;                // 64 KB
  int* deg    = (int*)p;     p += (size_t)N_NODES * 4;          // 400 KB
  int* bcnt   = (int*)p;     p += 256 * 4;                      // 1 KB
  int* pairs  = (int*)p;     p += (size_t)NBKT * CAP * 4;       // 9.6 MB
  int* ssrc   = (int*)p;                                        // N * capn * 4

  size_t base_used = (size_t)(p - (char*)d_ws);
  // capn=64: overflow P ~1e-11 for Poisson(16) max over 100k nodes.
  int capn = 40;
  if (ws_size >= base_used + (size_t)N_NODES * 64 * 4) capn = 64;
  else if (ws_size >= base_used + (size_t)N_NODES * 48 * 4) capn = 48;

  hipMemsetAsync(bcnt, 0, NBKT * sizeof(int), stream);
  passA_kernel<<<PA_BLOCKS + PACK_BLOCKS, 512, 0, stream>>>(
      erow, ecol, W_l, W_r, Bp, bcnt, pairs);
  passB_kernel<<<PB_BLOCKS + CVT_BLOCKS, 1024, 0, stream>>>(
      pairs, bcnt, x, xh, deg, ssrc, capn);
  fused_kernel<<<N_NODES / 32, 256, 0, stream>>>(xh, deg, ssrc, Bp, b_l, out, capn);
}

// Round 5
// 216.302 us; speedup vs baseline: 1.0545x; 1.0545x over previous
//
#include <hip/hip_runtime.h>

#define N_NODES 100000
#define E_EDGES 1600000
#define C 128
#define BSHIFT 9
#define BMASK 511
#define BNODES 512
#define NBKT 196        // ceil(N/512) buckets

#define PA2_BLOCKS 196  // passA: 8192 edges per 512-thr block (16 edges/thread)
#define CAP2 80         // per-(bucket,block) run capacity: Binom mean 41.8, sigma 6.45 -> 5.9 sigma
#define RUNSTRIDE (PA2_BLOCKS * CAP2)   // 15680 slots per bucket stripe

#define PB_BLOCKS 196    // passB role (1024-thr): one block per bucket
#define CVT_BLOCKS 1563  // cvt role (1024-thr): 1.6M uint4
#define PACK_BLOCKS 4    // pack role (1024-thr): 4096 frag-items

typedef __attribute__((ext_vector_type(8))) short short8;   // 8 bf16 (4 VGPRs)
typedef __attribute__((ext_vector_type(4))) float f32x4;    // MFMA acc

__device__ __forceinline__ unsigned short f2bf(float f) {  // RNE fp32->bf16
  unsigned int b = __float_as_uint(f);
  return (unsigned short)((b + 0x7fffu + ((b >> 16) & 1u)) >> 16);
}
__device__ __forceinline__ float bflo(unsigned int v) {
  return __uint_as_float(v << 16);
}
__device__ __forceinline__ float bfhi(unsigned int v) {
  return __uint_as_float(v & 0xffff0000u);
}

// ---------------------------------------------------------------------------
// passA (R5): STATIC-LAYOUT multisplit. The ~90us invariant across R0-R4 is
// attributed to the dynamic bucket allocator: ~77k returning device-scope
// atomicAdds on 13 cache lines (bcnt), serialized cross-XCD. R5 removes ALL
// global atomics: block bid owns the fixed run pairs[(bk*196+bid)*80 .. +80)
// per bucket bk; rank comes from an LDS atomic only. No scan, no barrier in
// the hot path, no memset dependency. Run lengths -> cntmat (150 KB).
// Own dispatch: if this still costs >50us it shows up in top-5 (tripwire).
// ---------------------------------------------------------------------------
__global__ __launch_bounds__(512) void passA_kernel(
    const int* __restrict__ erow, const int* __restrict__ ecol,
    int* __restrict__ pairs, int* __restrict__ cntmat) {
  __shared__ int cnt[NBKT];
  int bid = blockIdx.x;
  int tid = threadIdx.x;

  for (int b = tid; b < NBKT; b += 512) cnt[b] = 0;
  __syncthreads();

#pragma unroll
  for (int k = 0; k < 4; ++k) {
    int idx = bid * 2048 + k * 512 + tid;   // int4 index
    if (idx < E_EDGES / 4) {
      int4 r = ((const int4*)erow)[idx];
      int4 c = ((const int4*)ecol)[idx];
      int d[4] = {r.x, r.y, r.z, r.w};
      int s[4] = {c.x, c.y, c.z, c.w};
#pragma unroll
      for (int i = 0; i < 4; ++i) {
        int bk = d[i] >> BSHIFT;
        int rk = atomicAdd(&cnt[bk], 1);
        if (rk < CAP2)
          pairs[(bk * PA2_BLOCKS + bid) * CAP2 + rk] =
              (s[i] << BSHIFT) | (d[i] & BMASK);
      }
    }
  }
  __syncthreads();
  for (int b = tid; b < NBKT; b += 512) cntmat[bid * NBKT + b] = cnt[b];
}

// ---------------------------------------------------------------------------
// Dispatch 2: passB (padded-CSR build from static runs) + cvt + pack.
// passB: bucket b's data is the contiguous stripe pairs[b*15680 .. +15680);
// flat-index scan (run = e/80, off = e%80, valid iff off < llen[run]),
// LDS-atomic slot alloc per node, ssrc writes bucket-private (R2-verified
// pattern). cvt fills the machine while 196 passB blocks run.
// ---------------------------------------------------------------------------
__global__ __launch_bounds__(1024) void passB_kernel(
    const int* __restrict__ pairs, const int* __restrict__ cntmat,
    const float* __restrict__ x, const float* __restrict__ W_l,
    const float* __restrict__ W_r, ushort* __restrict__ xh,
    ushort* __restrict__ Bp, int* __restrict__ deg, int* __restrict__ ssrc,
    int capn) {
  int bid = blockIdx.x;
  int t = threadIdx.x;

  if (bid < PB_BLOCKS) {
    __shared__ int l[BNODES];
    __shared__ int llen[PA2_BLOCKS];
    int b = bid;
    if (t < BNODES) l[t] = 0;
    if (t < PA2_BLOCKS) llen[t] = min(cntmat[t * NBKT + b], CAP2);
    __syncthreads();

    int nbase = b << BSHIFT;
    int nn = min(BNODES, N_NODES - nbase);
    const int* bp = pairs + b * RUNSTRIDE;
    int wbase = nbase * capn;

    for (int e = t; e < RUNSTRIDE; e += 1024) {
      int run = e / CAP2;          // compile-time const div -> magic mul
      int off = e - run * CAP2;
      if (off < llen[run]) {
        int p = bp[e];
        int loc = p & BMASK;
        int slot = atomicAdd(&l[loc], 1);
        if (slot < capn) ssrc[wbase + loc * capn + slot] = p >> BSHIFT;
      }
    }
    __syncthreads();
    if (t < nn) deg[nbase + t] = l[t];
  } else if (bid < PB_BLOCKS + CVT_BLOCKS) {
    // ---- cvt: x fp32 -> xh bf16 (77 MB stream).
    int t2 = (bid - PB_BLOCKS) * 1024 + t;
    if (t2 < (N_NODES * C) / 8) {
      float4 a = ((const float4*)x)[2 * t2];
      float4 b = ((const float4*)x)[2 * t2 + 1];
      ushort u[8] = {f2bf(a.x), f2bf(a.y), f2bf(a.z), f2bf(a.w),
                     f2bf(b.x), f2bf(b.y), f2bf(b.z), f2bf(b.w)};
      ((uint4*)xh)[t2] = *(const uint4*)u;
    }
  } else {
    // ---- pack Wcat=[W_l;W_r] into MFMA B-fragment order.
    int tt = (bid - PB_BLOCKS - CVT_BLOCKS) * 1024 + t;  // tt < 4096
    int Cb = tt >> 9, kb = (tt >> 6) & 7, lane = tt & 63;
    int n = Cb * 16 + (lane & 15);
    int k0 = kb * 32 + (lane >> 4) * 8;
    ushort u[8];
#pragma unroll
    for (int j = 0; j < 8; ++j) {
      int k = k0 + j;
      float w = (k < C) ? W_l[k * C + n] : W_r[(k - C) * C + n];
      u[j] = f2bf(w);
    }
    ((uint4*)Bp)[tt] = *(const uint4*)u;
  }
}

// ---------------------------------------------------------------------------
// Fused gather-mean + MFMA GEMM:  out = relu([agg|x] @ [W_l;W_r] + b_l)
// EXACT R2-verified form (78.4us, VGPR 32, occ 63%): 2-deep uint4 gather.
// R4's 4-deep variant regressed (VGPR 40, occ 48%) -> reverted.
// ---------------------------------------------------------------------------
__global__ __launch_bounds__(256) void fused_kernel(
    const ushort* __restrict__ xh, const int* __restrict__ deg,
    const int* __restrict__ ssrc, const ushort* __restrict__ Bp,
    const float* __restrict__ b_l, float* __restrict__ out, int capn) {
  __shared__ ushort lA[32][264];
  int tid = threadIdx.x;
  int lane = tid & 63;
  int wave = tid >> 6;
  long base = (long)blockIdx.x * 32;

  for (int i = tid; i < 32 * 16; i += 256) {
    int r = i >> 4, q = i & 15;
    uint4 v = ((const uint4*)(xh + (base + r) * C))[q];
    *(uint4*)&lA[r][128 + q * 8] = v;
  }

  int l4 = lane & 15;   // channel group: ch [l4*8, l4*8+8)
  int q = lane >> 4;    // quarter: edge stripe

  for (int j = 0; j < 8; ++j) {
    int n = wave * 8 + j;
    int row = (int)base + n;
    int dg = deg[row];
    int e0 = row * capn;                 // <= 100000*64, fits int
    int e1 = e0 + min(dg, capn);
    float s[8];
#pragma unroll
    for (int i = 0; i < 8; ++i) s[i] = 0.0f;

    int e = e0 + q;
    for (; e + 4 < e1; e += 8) {  // 2 uint4 loads in flight per lane
      int sa = ssrc[e];
      int sb = ssrc[e + 4];
      uint4 va = ((const uint4*)(xh + (long)sa * C))[l4];
      uint4 vb = ((const uint4*)(xh + (long)sb * C))[l4];
      s[0] += bflo(va.x) + bflo(vb.x); s[1] += bfhi(va.x) + bfhi(vb.x);
      s[2] += bflo(va.y) + bflo(vb.y); s[3] += bfhi(va.y) + bfhi(vb.y);
      s[4] += bflo(va.z) + bflo(vb.z); s[5] += bfhi(va.z) + bfhi(vb.z);
      s[6] += bflo(va.w) + bflo(vb.w); s[7] += bfhi(va.w) + bfhi(vb.w);
    }
    if (e < e1) {
      int sa = ssrc[e];
      uint4 va = ((const uint4*)(xh + (long)sa * C))[l4];
      s[0] += bflo(va.x); s[1] += bfhi(va.x);
      s[2] += bflo(va.y); s[3] += bfhi(va.y);
      s[4] += bflo(va.z); s[5] += bfhi(va.z);
      s[6] += bflo(va.w); s[7] += bfhi(va.w);
    }
#pragma unroll
    for (int i = 0; i < 8; ++i) {
      s[i] += __shfl_xor(s[i], 16);
      s[i] += __shfl_xor(s[i], 32);
    }
    float inv = 1.0f / fmaxf((float)dg, 1.0f);  // true degree (mean agg)
    if (q == 0) {
      ushort u[8];
#pragma unroll
      for (int i = 0; i < 8; ++i) u[i] = f2bf(s[i] * inv);
      *(uint4*)&lA[n][l4 * 8] = *(const uint4*)u;
    }
  }
  __syncthreads();

  f32x4 acc0 = {0, 0, 0, 0}, acc1 = {0, 0, 0, 0};
  f32x4 acc2 = {0, 0, 0, 0}, acc3 = {0, 0, 0, 0};
  int m = lane & 15, quad = lane >> 4;
  const ushort* bp0 = Bp + (((2 * wave + 0) * 8) * 64 + lane) * 8;
  const ushort* bp1 = Bp + (((2 * wave + 1) * 8) * 64 + lane) * 8;
#pragma unroll
  for (int kb = 0; kb < 8; ++kb) {
    short8 a0 = *(const short8*)&lA[m][kb * 32 + quad * 8];
    short8 a1 = *(const short8*)&lA[16 + m][kb * 32 + quad * 8];
    short8 b0 = *(const short8*)(bp0 + kb * 64 * 8);
    short8 b1 = *(const short8*)(bp1 + kb * 64 * 8);
    acc0 = __builtin_amdgcn_mfma_f32_16x16x32_bf16(a0, b0, acc0, 0, 0, 0);
    acc1 = __builtin_amdgcn_mfma_f32_16x16x32_bf16(a0, b1, acc1, 0, 0, 0);
    acc2 = __builtin_amdgcn_mfma_f32_16x16x32_bf16(a1, b0, acc2, 0, 0, 0);
    acc3 = __builtin_amdgcn_mfma_f32_16x16x32_bf16(a1, b1, acc3, 0, 0, 0);
  }

  int col0 = (2 * wave + 0) * 16 + m;
  int col1 = col0 + 16;
  float bl0 = b_l[col0], bl1 = b_l[col1];
#pragma unroll
  for (int r = 0; r < 4; ++r) {
    long row0 = base + quad * 4 + r;
    long row1 = row0 + 16;
    out[row0 * C + col0] = fmaxf(acc0[r] + bl0, 0.0f);
    out[row0 * C + col1] = fmaxf(acc1[r] + bl1, 0.0f);
    out[row1 * C + col0] = fmaxf(acc2[r] + bl0, 0.0f);
    out[row1 * C + col1] = fmaxf(acc3[r] + bl1, 0.0f);
  }
}

extern "C" void kernel_launch(void* const* d_in, const int* in_sizes, int n_in,
                              void* d_out, int out_size, void* d_ws, size_t ws_size,
                              hipStream_t stream) {
  const float* x   = (const float*)d_in[0];
  const int* erow  = (const int*)d_in[1];   // dst
  const int* ecol  = (const int*)d_in[2];   // src
  const float* W_l = (const float*)d_in[3];
  const float* b_l = (const float*)d_in[4];
  const float* W_r = (const float*)d_in[5];
  float* out = (float*)d_out;

  char* p = (char*)d_ws;
  ushort* xh  = (ushort*)p;  p += (size_t)N_NODES * C * 2;           // 25.6 MB
  ushort* Bp  = (ushort*)p;  p += 2 * C * C * 2;                     // 64 KB
  int* deg    = (int*)p;     p += (size_t)N_NODES * 4;               // 400 KB
  int* cntmat = (int*)p;     p += (size_t)PA2_BLOCKS * NBKT * 4;     // 150 KB
  int* pairs  = (int*)p;     p += (size_t)NBKT * RUNSTRIDE * 4;      // 12.3 MB
  int* ssrc   = (int*)p;                                             // N * capn * 4

  size_t base_used = (size_t)(p - (char*)d_ws);
  // capn=64: overflow P ~1e-11 for Poisson(16) max over 100k nodes.
  int capn = 40;
  if (ws_size >= base_used + (size_t)N_NODES * 64 * 4) capn = 64;
  else if (ws_size >= base_used + (size_t)N_NODES * 48 * 4) capn = 48;

  // No memset: cntmat fully written by passA, deg fully written by passB.
  passA_kernel<<<PA2_BLOCKS, 512, 0, stream>>>(erow, ecol, pairs, cntmat);
  passB_kernel<<<PB_BLOCKS + CVT_BLOCKS + PACK_BLOCKS, 1024, 0, stream>>>(
      pairs, cntmat, x, W_l, W_r, xh, Bp, deg, ssrc, capn);
  fused_kernel<<<N_NODES / 32, 256, 0, stream>>>(xh, deg, ssrc, Bp, b_l, out, capn);
}

// Round 8
// 205.624 us; speedup vs baseline: 1.1093x; 1.0519x over previous
//
#include <hip/hip_runtime.h>

#define N_NODES 100000
#define E_EDGES 1600000
#define C 128
#define BSHIFT 9
#define BMASK 511
#define BNODES 512
#define NBKT 196                      // ceil(N/512) buckets

#define PA_BLOCKS 196                 // passA: 8192 edges per 512-thr block
#define CAP2 80                       // per-(bucket,block) run cap: mean 41.8, +5.9 sigma
#define RUNSTRIDE (PA_BLOCKS * CAP2)  // 15680 slots per bucket stripe
#define PACK_BLOCKS 8                 // pack role in D1

#define PB_BLOCKS 196                 // passB role (1024 thr): one block per bucket
#define CVT_BLOCKS 1563               // cvt role (1024 thr): 1.6M uint4
#define BCAP 8704                     // compact per-bucket ssrc cap: mean 8192 + 5.7 sigma

typedef __attribute__((ext_vector_type(8))) short short8;   // 8 bf16 (4 VGPRs)
typedef __attribute__((ext_vector_type(4))) float f32x4;    // MFMA acc

__device__ __forceinline__ unsigned short f2bf(float f) {  // RNE fp32->bf16
  unsigned int b = __float_as_uint(f);
  return (unsigned short)((b + 0x7fffu + ((b >> 16) & 1u)) >> 16);
}
__device__ __forceinline__ float bflo(unsigned int v) {
  return __uint_as_float(v << 16);
}
__device__ __forceinline__ float bfhi(unsigned int v) {
  return __uint_as_float(v & 0xffff0000u);
}

// ---------------------------------------------------------------------------
// D1: passA-static (R5-verified: no global atomics, no memset dependency)
// + W-pack. Block bid owns fixed run pairs[(bk*196+bid)*80 .. +80) per
// bucket; rank from LDS atomic only; run lengths -> cntmat.
// (R8 = resubmit of R7: container failure audit found no kernel mechanism;
// all components previously harness-verified. Infra-flake hypothesis.)
// ---------------------------------------------------------------------------
__global__ __launch_bounds__(512) void passA_kernel(
    const int* __restrict__ erow, const int* __restrict__ ecol,
    const float* __restrict__ W_l, const float* __restrict__ W_r,
    ushort* __restrict__ Bp, int* __restrict__ pairs,
    int* __restrict__ cntmat) {
  __shared__ int cnt[NBKT];
  int bid = blockIdx.x;
  int tid = threadIdx.x;

  if (bid < PA_BLOCKS) {
    for (int b = tid; b < NBKT; b += 512) cnt[b] = 0;
    __syncthreads();

#pragma unroll
    for (int k = 0; k < 4; ++k) {
      int idx = bid * 2048 + k * 512 + tid;   // int4 index
      if (idx < E_EDGES / 4) {
        int4 r = ((const int4*)erow)[idx];
        int4 c = ((const int4*)ecol)[idx];
        int d[4] = {r.x, r.y, r.z, r.w};
        int s[4] = {c.x, c.y, c.z, c.w};
#pragma unroll
        for (int i = 0; i < 4; ++i) {
          int bk = d[i] >> BSHIFT;
          int rk = atomicAdd(&cnt[bk], 1);
          if (rk < CAP2)
            pairs[(bk * PA_BLOCKS + bid) * CAP2 + rk] =
                (s[i] << BSHIFT) | (d[i] & BMASK);
        }
      }
    }
    __syncthreads();
    for (int b = tid; b < NBKT; b += 512) cntmat[bid * NBKT + b] = cnt[b];
  } else {
    // ---- pack Wcat=[W_l;W_r] into MFMA B-fragment order (R0-verified).
    int t = (bid - PA_BLOCKS) * 512 + tid;  // t < 4096
    int Cb = t >> 9, kb = (t >> 6) & 7, lane = t & 63;
    int n = Cb * 16 + (lane & 15);
    int k0 = kb * 32 + (lane >> 4) * 8;
    ushort u[8];
#pragma unroll
    for (int j = 0; j < 8; ++j) {
      int k = k0 + j;
      float w = (k < C) ? W_l[k * C + n] : W_r[(k - C) * C + n];
      u[j] = f2bf(w);
    }
    ((uint4*)Bp)[t] = *(const uint4*)u;
  }
}

// ---------------------------------------------------------------------------
// D2: passB-compact + cvt co-dispatched (R2's machine-filling pattern).
// passB (bid < 196): count (pass 1 over static stripe) -> Hillis scan of 512
// degrees (R0-verified pattern) -> scatter into COMPACT per-bucket ssrc
// window [b*BCAP ..). Emits offv[node], deg[node]. Stripe is 61 KB,
// L2-resident; read twice. cvt (bid >= 196) fills the other CUs.
// ---------------------------------------------------------------------------
__global__ __launch_bounds__(1024) void passB_kernel(
    const int* __restrict__ pairs, const int* __restrict__ cntmat,
    const float* __restrict__ x, ushort* __restrict__ xh,
    int* __restrict__ deg, int* __restrict__ offv, int* __restrict__ ssrc) {
  int bid = blockIdx.x;
  int t = threadIdx.x;

  if (bid < PB_BLOCKS) {
    __shared__ int l[BNODES];
    __shared__ int cur[BNODES];
    __shared__ int llen[PA_BLOCKS];
    int b = bid;
    if (t < BNODES) l[t] = 0;
    for (int r = t; r < PA_BLOCKS; r += 1024)
      llen[r] = min(cntmat[r * NBKT + b], CAP2);
    __syncthreads();

    const int* bp = pairs + b * RUNSTRIDE;
    // pass 1: per-node degree count from the static stripe.
    for (int e = t; e < RUNSTRIDE; e += 1024) {
      int run = e / CAP2;            // const div -> magic mul
      int off = e - run * CAP2;
      if (off < llen[run]) {
        int p = bp[e];
        atomicAdd(&l[p & BMASK], 1);
      }
    }
    __syncthreads();

    int own = (t < BNODES) ? l[t] : 0;
    for (int d = 1; d < BNODES; d <<= 1) {  // Hillis inclusive scan (R0 form)
      int u = (t < BNODES && t >= d) ? l[t - d] : 0;
      __syncthreads();
      if (t < BNODES) l[t] += u;
      __syncthreads();
    }
    if (t < BNODES) {
      int excl = l[t] - own;
      int nbase = b << BSHIFT;
      int node = nbase + t;
      int ex = min(excl, BCAP);
      int dg = min(own, BCAP - ex);   // clamped so window stays in stripe
      if (node < N_NODES) {
        offv[node] = b * BCAP + ex;
        deg[node] = dg;
      }
      cur[t] = excl;
    }
    __syncthreads();

    // pass 2: scatter into compact per-bucket ssrc.
    for (int e = t; e < RUNSTRIDE; e += 1024) {
      int run = e / CAP2;
      int off = e - run * CAP2;
      if (off < llen[run]) {
        int p = bp[e];
        int s = atomicAdd(&cur[p & BMASK], 1);
        if (s < BCAP) ssrc[b * BCAP + s] = p >> BSHIFT;
      }
    }
  } else {
    // ---- cvt: x fp32 -> xh bf16 (77 MB stream, verified).
    int t2 = (bid - PB_BLOCKS) * 1024 + t;
    if (t2 < (N_NODES * C) / 8) {
      float4 a = ((const float4*)x)[2 * t2];
      float4 b = ((const float4*)x)[2 * t2 + 1];
      ushort u[8] = {f2bf(a.x), f2bf(a.y), f2bf(a.z), f2bf(a.w),
                     f2bf(b.x), f2bf(b.y), f2bf(b.z), f2bf(b.w)};
      ((uint4*)xh)[t2] = *(const uint4*)u;
    }
  }
}

// ---------------------------------------------------------------------------
// Fused gather-mean + MFMA GEMM:  out = relu([agg|x] @ [W_l;W_r] + b_l)
// R0's verified 74.6us form (VGPR 32, occ 63%, 2-deep gather, COMPACT CSR);
// addressing via offv[row] + deg[row].
// ---------------------------------------------------------------------------
__global__ __launch_bounds__(256) void fused_kernel(
    const ushort* __restrict__ xh, const int* __restrict__ deg,
    const int* __restrict__ offv, const int* __restrict__ ssrc,
    const ushort* __restrict__ Bp, const float* __restrict__ b_l,
    float* __restrict__ out) {
  __shared__ ushort lA[32][264];
  int tid = threadIdx.x;
  int lane = tid & 63;
  int wave = tid >> 6;
  long base = (long)blockIdx.x * 32;

  for (int i = tid; i < 32 * 16; i += 256) {
    int r = i >> 4, q = i & 15;
    uint4 v = ((const uint4*)(xh + (base + r) * C))[q];
    *(uint4*)&lA[r][128 + q * 8] = v;
  }

  int l4 = lane & 15;   // channel group: ch [l4*8, l4*8+8)
  int q = lane >> 4;    // quarter: edge stripe

  for (int j = 0; j < 8; ++j) {
    int n = wave * 8 + j;
    int row = (int)base + n;
    int dg = deg[row];
    int e0 = offv[row];
    int e1 = e0 + dg;
    float s[8];
#pragma unroll
    for (int i = 0; i < 8; ++i) s[i] = 0.0f;

    int e = e0 + q;
    for (; e + 4 < e1; e += 8) {  // 2 uint4 loads in flight per lane
      int sa = ssrc[e];
      int sb = ssrc[e + 4];
      uint4 va = ((const uint4*)(xh + (long)sa * C))[l4];
      uint4 vb = ((const uint4*)(xh + (long)sb * C))[l4];
      s[0] += bflo(va.x) + bflo(vb.x); s[1] += bfhi(va.x) + bfhi(vb.x);
      s[2] += bflo(va.y) + bflo(vb.y); s[3] += bfhi(va.y) + bfhi(vb.y);
      s[4] += bflo(va.z) + bflo(vb.z); s[5] += bfhi(va.z) + bfhi(vb.z);
      s[6] += bflo(va.w) + bflo(vb.w); s[7] += bfhi(va.w) + bfhi(vb.w);
    }
    if (e < e1) {
      int sa = ssrc[e];
      uint4 va = ((const uint4*)(xh + (long)sa * C))[l4];
      s[0] += bflo(va.x); s[1] += bfhi(va.x);
      s[2] += bflo(va.y); s[3] += bfhi(va.y);
      s[4] += bflo(va.z); s[5] += bfhi(va.z);
      s[6] += bflo(va.w); s[7] += bfhi(va.w);
    }
#pragma unroll
    for (int i = 0; i < 8; ++i) {
      s[i] += __shfl_xor(s[i], 16);
      s[i] += __shfl_xor(s[i], 32);
    }
    float inv = 1.0f / fmaxf((float)dg, 1.0f);  // true degree (mean agg)
    if (q == 0) {
      ushort u[8];
#pragma unroll
      for (int i = 0; i < 8; ++i) u[i] = f2bf(s[i] * inv);
      *(uint4*)&lA[n][l4 * 8] = *(const uint4*)u;
    }
  }
  __syncthreads();

  f32x4 acc0 = {0, 0, 0, 0}, acc1 = {0, 0, 0, 0};
  f32x4 acc2 = {0, 0, 0, 0}, acc3 = {0, 0, 0, 0};
  int m = lane & 15, quad = lane >> 4;
  const ushort* bp0 = Bp + (((2 * wave + 0) * 8) * 64 + lane) * 8;
  const ushort* bp1 = Bp + (((2 * wave + 1) * 8) * 64 + lane) * 8;
#pragma unroll
  for (int kb = 0; kb < 8; ++kb) {
    short8 a0 = *(const short8*)&lA[m][kb * 32 + quad * 8];
    short8 a1 = *(const short8*)&lA[16 + m][kb * 32 + quad * 8];
    short8 b0 = *(const short8*)(bp0 + kb * 64 * 8);
    short8 b1 = *(const short8*)(bp1 + kb * 64 * 8);
    acc0 = __builtin_amdgcn_mfma_f32_16x16x32_bf16(a0, b0, acc0, 0, 0, 0);
    acc1 = __builtin_amdgcn_mfma_f32_16x16x32_bf16(a0, b1, acc1, 0, 0, 0);
    acc2 = __builtin_amdgcn_mfma_f32_16x16x32_bf16(a1, b0, acc2, 0, 0, 0);
    acc3 = __builtin_amdgcn_mfma_f32_16x16x32_bf16(a1, b1, acc3, 0, 0, 0);
  }

  int col0 = (2 * wave + 0) * 16 + m;
  int col1 = col0 + 16;
  float bl0 = b_l[col0], bl1 = b_l[col1];
#pragma unroll
  for (int r = 0; r < 4; ++r) {
    long row0 = base + quad * 4 + r;
    long row1 = row0 + 16;
    out[row0 * C + col0] = fmaxf(acc0[r] + bl0, 0.0f);
    out[row0 * C + col1] = fmaxf(acc1[r] + bl1, 0.0f);
    out[row1 * C + col0] = fmaxf(acc2[r] + bl0, 0.0f);
    out[row1 * C + col1] = fmaxf(acc3[r] + bl1, 0.0f);
  }
}

extern "C" void kernel_launch(void* const* d_in, const int* in_sizes, int n_in,
                              void* d_out, int out_size, void* d_ws, size_t ws_size,
                              hipStream_t stream) {
  const float* x   = (const float*)d_in[0];
  const int* erow  = (const int*)d_in[1];   // dst
  const int* ecol  = (const int*)d_in[2];   // src
  const float* W_l = (const float*)d_in[3];
  const float* b_l = (const float*)d_in[4];
  const float* W_r = (const float*)d_in[5];
  float* out = (float*)d_out;

  char* p = (char*)d_ws;
  ushort* xh  = (ushort*)p;  p += (size_t)N_NODES * C * 2;           // 25.6 MB
  ushort* Bp  = (ushort*)p;  p += 2 * C * C * 2;                     // 64 KB
  int* deg    = (int*)p;     p += (size_t)N_NODES * 4;               // 400 KB
  int* offv   = (int*)p;     p += (size_t)N_NODES * 4;               // 400 KB
  int* cntmat = (int*)p;     p += (size_t)PA_BLOCKS * NBKT * 4;      // 154 KB
  int* pairs  = (int*)p;     p += (size_t)NBKT * RUNSTRIDE * 4;      // 12.3 MB
  int* ssrc   = (int*)p;                                             // 6.8 MB
  // total ~45.7 MB (R5's ~64 MB footprint passed, so ws_size suffices)

  // No memset, no cooperative launch (R6 lesson: breaks graph capture).
  passA_kernel<<<PA_BLOCKS + PACK_BLOCKS, 512, 0, stream>>>(
      erow, ecol, W_l, W_r, Bp, pairs, cntmat);
  passB_kernel<<<PB_BLOCKS + CVT_BLOCKS, 1024, 0, stream>>>(
      pairs, cntmat, x, xh, deg, offv, ssrc);
  fused_kernel<<<N_NODES / 32, 256, 0, stream>>>(xh, deg, offv, ssrc, Bp, b_l,
                                                 out);
}